// Round 6
// baseline (33.264 us; speedup 1.0000x reference)
//
#include <hip/hip_runtime.h>
#include <hip/hip_bf16.h>
#include <math.h>

// Problem constants (fixed by setup_inputs)
constexpr int B_ = 16, S_ = 512, T_ = 4096, E_ = 256;

typedef __attribute__((ext_vector_type(8))) short short8;
typedef __attribute__((ext_vector_type(4))) float f32x4;

// Workspace layout (bytes)
constexpr size_t FLAGS_OFF = 0;             // 32 ints
constexpr size_t WT_OFF    = 4096;          // 256x256 bf16 W^T = 128KB
constexpr size_t PEW_OFF   = 256u * 1024;   // 4096x256 f32 = 4MB

// -ln(10000)/256
#define NEGC (-0.035977892f)

__device__ __forceinline__ unsigned pk_bf16(float a, float b) {
    __hip_bfloat162 h = __float22bfloat162_rn(make_float2(a, b));
    return *(unsigned*)&h;
}
__device__ __forceinline__ short bf16s(float x) {
    unsigned u = __float_as_uint(x);
    u += 0x7FFFu + ((u >> 16) & 1u);
    return (short)(u >> 16);
}

// ---------------------------------------------------------------------------
// Prep, roles by blockIdx.x:
//  [0,32)   aligner-recurrence validation (8 ids/thread, int4) -> flags[bid]
//  [32,48)  W^T -> bf16 wt
//  [48,304) PEW tiles: pew[t, n] = (PE @ W)[t, n] + bpos[n]  (64x64 per block)
__global__ __launch_bounds__(256) void k_prep(
    const int* __restrict__ align, const int* __restrict__ text,
    const float* __restrict__ W, const float* __restrict__ bpos,
    int* __restrict__ flags, short* __restrict__ wt, float* __restrict__ pew)
{
    const int bid = blockIdx.x, tid = threadIdx.x;
    if (bid < 32) {
        __shared__ int f;
        if (tid == 0) f = 0;
        __syncthreads();
        const int base = (bid * 256 + tid) * 8;
        const int4 a0 = *(const int4*)(align + base);
        const int4 a1 = *(const int4*)(align + base + 4);
        const int av[8] = {a0.x, a0.y, a0.z, a0.w, a1.x, a1.y, a1.z, a1.w};
        int bad = 0;
#pragma unroll
        for (int m = 0; m < 8; ++m) {
            const int id = base + m;
            const int t = id & (T_ - 1), b = id >> 12;
            if (t > 0) {
                const int prev = (t - 1) >> 3;
                const int expct = (av[m] == text[b * S_ + prev]) ? prev : min(prev + 1, S_ - 1);
                if ((t >> 3) != expct) bad = 1;
            }
        }
        if (bad) f = 1;                  // benign race: all writers store 1
        __syncthreads();
        if (tid == 0) flags[bid] = f;
        return;
    }
    if (bid < 48) {
        const int kb = (bid - 32) * 16;
        short8 v0, v1;
#pragma unroll
        for (int j = 0; j < 8; ++j) v0[j] = bf16s(W[(kb + j) * E_ + tid]);
#pragma unroll
        for (int j = 0; j < 8; ++j) v1[j] = bf16s(W[(kb + 8 + j) * E_ + tid]);
        *(short8*)(wt + tid * E_ + kb)     = v0;
        *(short8*)(wt + tid * E_ + kb + 8) = v1;
        return;
    }

    // ---- PEW tile: m0 = t-base, n0 = col base ----
    __shared__ __align__(16) short As[64 * 256];
    __shared__ __align__(16) short Bs[64 * 256];
    const int pid = bid - 48;
    const int m0 = (pid >> 2) * 64;
    const int n0 = (pid & 3) * 64;

    // stage Bs from W directly (transpose + cvt; no wt dependency)
    {
        const int k = tid;
        const float* wrow = W + (size_t)k * E_ + n0;
#pragma unroll
        for (int jj = 0; jj < 16; ++jj) {
            const float4 v = *(const float4*)(wrow + jj * 4);
            const int n = jj * 4;
            Bs[((n + 0) * 256 + k) ^ (((n + 0) & 7) << 3)] = bf16s(v.x);
            Bs[((n + 1) * 256 + k) ^ (((n + 1) & 7) << 3)] = bf16s(v.y);
            Bs[((n + 2) * 256 + k) ^ (((n + 2) & 7) << 3)] = bf16s(v.z);
            Bs[((n + 3) * 256 + k) ^ (((n + 3) & 7) << 3)] = bf16s(v.w);
        }
    }
    // stage As = PE rows m0..m0+64 (on-the-fly sincos)
    {
        const int r = tid >> 2, c4 = tid & 3;
        const float tf = (float)(m0 + r);
#pragma unroll
        for (int jj = 0; jj < 8; ++jj) {
            const int seg = c4 + 4 * jj;
            union { short8 v; unsigned u[4]; } cv;
#pragma unroll
            for (int m = 0; m < 4; ++m) {
                const int j2 = seg * 4 + m;
                const float d = __expf((float)(2 * j2) * NEGC);
                float s, c;
                __sincosf(tf * d, &s, &c);
                cv.u[m] = pk_bf16(s, c);
            }
            *(short8*)&As[(r * 256 + seg * 8) ^ ((r & 7) << 3)] = cv.v;
        }
    }
    __syncthreads();

    const int wid = tid >> 6, lane = tid & 63;
    const int q = lane >> 4, c = lane & 15;
    const int wm = (wid >> 1) << 5, wn = (wid & 1) << 5;
    f32x4 acc[2][2] = {{{0.f, 0.f, 0.f, 0.f}, {0.f, 0.f, 0.f, 0.f}},
                       {{0.f, 0.f, 0.f, 0.f}, {0.f, 0.f, 0.f, 0.f}}};
#pragma unroll
    for (int ks = 0; ks < 8; ++ks) {
        const int kidx = ks * 32 + q * 8;
        const int ra0 = wm + c, ra1 = wm + 16 + c;
        const int rb0 = wn + c, rb1 = wn + 16 + c;
        short8 a0 = *(const short8*)&As[(ra0 * 256 + kidx) ^ ((ra0 & 7) << 3)];
        short8 a1 = *(const short8*)&As[(ra1 * 256 + kidx) ^ ((ra1 & 7) << 3)];
        short8 b0 = *(const short8*)&Bs[(rb0 * 256 + kidx) ^ ((rb0 & 7) << 3)];
        short8 b1 = *(const short8*)&Bs[(rb1 * 256 + kidx) ^ ((rb1 & 7) << 3)];
        acc[0][0] = __builtin_amdgcn_mfma_f32_16x16x32_bf16(a0, b0, acc[0][0], 0, 0, 0);
        acc[0][1] = __builtin_amdgcn_mfma_f32_16x16x32_bf16(a0, b1, acc[0][1], 0, 0, 0);
        acc[1][0] = __builtin_amdgcn_mfma_f32_16x16x32_bf16(a1, b0, acc[1][0], 0, 0, 0);
        acc[1][1] = __builtin_amdgcn_mfma_f32_16x16x32_bf16(a1, b1, acc[1][1], 0, 0, 0);
    }
    const int gcol0 = n0 + wn + c, gcol1 = gcol0 + 16;
    const float bp0 = bpos[gcol0], bp1 = bpos[gcol1];
#pragma unroll
    for (int mt = 0; mt < 2; ++mt)
#pragma unroll
        for (int rr = 0; rr < 4; ++rr) {
            const int t = m0 + wm + mt * 16 + q * 4 + rr;
            pew[(size_t)t * E_ + gcol0] = acc[mt][0][rr] + bp0;
            pew[(size_t)t * E_ + gcol1] = acc[mt][1][rr] + bp1;
        }
}

// ---------------------------------------------------------------------------
// Fused GEMM. Block = 4 phones x 16 batches x 64 N-cols. LDS = Bs only (32KB);
// A-fragments load straight from enc (global, L2/L3) with in-register cvt.
__global__ __launch_bounds__(256) void k_fused(
    const float* __restrict__ enc, const short* __restrict__ wt,
    const float* __restrict__ pew,
    const float* __restrict__ pitch, const int* __restrict__ beats,
    const float* __restrict__ wpitch, const float* __restrict__ bpitch,
    const float* __restrict__ embb,
    const float* __restrict__ W, const int* __restrict__ align,
    const int* __restrict__ text, const int* __restrict__ flags,
    const float* __restrict__ bpos, float* __restrict__ out)
{
    __shared__ __align__(16) short Bs[64 * 256];   // 32KB; reused as f32 ew[64][68]

    const int tid = threadIdx.x;
    const int i0 = blockIdx.x * 4;                 // phone base
    const int n0 = blockIdx.y * 64;
    const int t0base = i0 * 8;

    // ---- fallback flag (never set for this data) ----
    const bool fb = __any(flags[tid & 31] != 0);
    if (fb) {
        int (*idxl)[32] = (int(*)[32])Bs;          // alias; fast path not taken
        if (tid < 16) {
            int i = 0;
            const int b = tid;
            if (i0 == 0) idxl[b][0] = 0;
            const int tmax = t0base + 32;
            for (int t = 1; t < tmax; ++t) {
                if (align[b * T_ + t] != text[b * S_ + i]) i = min(i + 1, S_ - 1);
                if (t >= t0base) idxl[b][t - t0base] = i;
            }
        }
        __syncthreads();
        for (int r = tid; r < 512; r += 256) {
            const int bq = r >> 5, tt = r & 31;
            const int t = t0base + tt;
            const int i = idxl[bq][tt];
            const float* erow = enc + (size_t)(bq * S_ + i) * E_;
            const float p = pitch[(size_t)bq * T_ + t];
            const int bt = beats[(size_t)bq * T_ + t];
            for (int cc = 0; cc < 64; ++cc) {
                const int col = n0 + cc;
                float acc = 0.f;
                for (int k2 = 0; k2 < 128; ++k2) {
                    const float d = __expf((float)(2 * k2) * NEGC);
                    float s, c;
                    __sincosf((float)t * d, &s, &c);
                    acc += (erow[2 * k2] + s) * W[(2 * k2) * E_ + col]
                         + (erow[2 * k2 + 1] + c) * W[(2 * k2 + 1) * E_ + col];
                }
                out[((size_t)bq * T_ + t) * E_ + col] =
                    erow[col] + acc + bpos[col] + p * wpitch[col] + bpitch[col]
                    + (bt ? embb[E_ + col] : embb[col]);
            }
        }
        return;
    }

    // ---- stage B: wt rows n0..n0+64 (vector, swizzled) ----
    {
        const int r = tid >> 2, c4 = tid & 3;
        const short* bp = wt + (size_t)(n0 + r) * E_;
#pragma unroll
        for (int jj = 0; jj < 8; ++jj) {
            const int seg = c4 + 4 * jj;
            short8 v = *(const short8*)(bp + seg * 8);
            *(short8*)&Bs[(r * 256 + seg * 8) ^ ((r & 7) << 3)] = v;
        }
    }
    __syncthreads();

    // ---- MFMA: A-fragments straight from enc (per-lane 32B rows, cvt) ----
    const int wid = tid >> 6, lane = tid & 63;
    const int q = lane >> 4, c = lane & 15;
    const int wm = (wid >> 1) << 5, wn = (wid & 1) << 5;
    const int ra0 = wm + c, ra1 = wm + 16 + c;
    const int rb0 = wn + c, rb1 = wn + 16 + c;
    const float* ap0 = enc + (size_t)((ra0 >> 2) * S_ + i0 + (ra0 & 3)) * E_;
    const float* ap1 = enc + (size_t)((ra1 >> 2) * S_ + i0 + (ra1 & 3)) * E_;

    f32x4 acc[2][2] = {{{0.f, 0.f, 0.f, 0.f}, {0.f, 0.f, 0.f, 0.f}},
                       {{0.f, 0.f, 0.f, 0.f}, {0.f, 0.f, 0.f, 0.f}}};
#pragma unroll
    for (int ks = 0; ks < 8; ++ks) {
        const int kidx = ks * 32 + q * 8;
        const float4 f0 = *(const float4*)(ap0 + kidx);
        const float4 f1 = *(const float4*)(ap0 + kidx + 4);
        const float4 g0 = *(const float4*)(ap1 + kidx);
        const float4 g1 = *(const float4*)(ap1 + kidx + 4);
        union { short8 v; unsigned u[4]; } a0, a1;
        a0.u[0] = pk_bf16(f0.x, f0.y); a0.u[1] = pk_bf16(f0.z, f0.w);
        a0.u[2] = pk_bf16(f1.x, f1.y); a0.u[3] = pk_bf16(f1.z, f1.w);
        a1.u[0] = pk_bf16(g0.x, g0.y); a1.u[1] = pk_bf16(g0.z, g0.w);
        a1.u[2] = pk_bf16(g1.x, g1.y); a1.u[3] = pk_bf16(g1.z, g1.w);
        short8 b0 = *(const short8*)&Bs[(rb0 * 256 + kidx) ^ ((rb0 & 7) << 3)];
        short8 b1 = *(const short8*)&Bs[(rb1 * 256 + kidx) ^ ((rb1 & 7) << 3)];
        acc[0][0] = __builtin_amdgcn_mfma_f32_16x16x32_bf16(a0.v, b0, acc[0][0], 0, 0, 0);
        acc[0][1] = __builtin_amdgcn_mfma_f32_16x16x32_bf16(a0.v, b1, acc[0][1], 0, 0, 0);
        acc[1][0] = __builtin_amdgcn_mfma_f32_16x16x32_bf16(a1.v, b0, acc[1][0], 0, 0, 0);
        acc[1][1] = __builtin_amdgcn_mfma_f32_16x16x32_bf16(a1.v, b1, acc[1][1], 0, 0, 0);
    }

    // ---- transpose acc through LDS (ew aliases Bs; Bs reads all done) ----
    __syncthreads();
    float* ew = (float*)Bs;
#pragma unroll
    for (int mt = 0; mt < 2; ++mt)
#pragma unroll
        for (int nh = 0; nh < 2; ++nh)
#pragma unroll
            for (int rr = 0; rr < 4; ++rr)
                ew[(wm + mt * 16 + q * 4 + rr) * 68 + wn + nh * 16 + c] = acc[mt][nh][rr];

    // pv loads (L2-resident pew; latency hides under transpose + barrier)
    const int c4o = tid & 15, rg = tid >> 4;
    const int gc = n0 + 4 * c4o;
    const int j = rg & 3;
    const int t0 = t0base + j * 8;
    f32x4 pv[8];
#pragma unroll
    for (int d = 0; d < 8; ++d)
        pv[d] = *(const f32x4*)(pew + (size_t)(t0 + d) * E_ + gc);
    const f32x4 wp4 = *(const f32x4*)(wpitch + gc);
    const f32x4 cst = *(const f32x4*)(bpitch + gc);
    const f32x4 be0 = *(const f32x4*)(embb + gc);
    const f32x4 be1 = *(const f32x4*)(embb + E_ + gc);
    __syncthreads();

    // ---- epilogue: per-p loads, nontemporal stores ----
#pragma unroll
    for (int p = 0; p < 4; ++p) {
        const int lrow = rg + p * 16;
        const int bq = lrow >> 2;
        const size_t prow = (size_t)bq * T_ + t0;
        const float4 pi0 = *(const float4*)(pitch + prow);
        const float4 pi1 = *(const float4*)(pitch + prow + 4);
        const int4  bt0 = *(const int4*)(beats + prow);
        const int4  bt1 = *(const int4*)(beats + prow + 4);
        const f32x4 e4  = *(const f32x4*)(enc + (size_t)(bq * S_ + i0 + j) * E_ + gc);
        const f32x4 ewv = *(const f32x4*)&ew[lrow * 68 + 4 * c4o];
        const f32x4 base = ewv + e4 + cst;
        const float pp[8] = {pi0.x, pi0.y, pi0.z, pi0.w, pi1.x, pi1.y, pi1.z, pi1.w};
        const int   bb[8] = {bt0.x, bt0.y, bt0.z, bt0.w, bt1.x, bt1.y, bt1.z, bt1.w};
#pragma unroll
        for (int d = 0; d < 8; ++d) {
            const f32x4 be = bb[d] ? be1 : be0;
            f32x4 o = base + pv[d] + pp[d] * wp4 + be;
            __builtin_nontemporal_store(o, (f32x4*)(out + (prow + d) * E_ + gc));
        }
    }
}

// ---------------------------------------------------------------------------
extern "C" void kernel_launch(void* const* d_in, const int* in_sizes, int n_in,
                              void* d_out, int out_size, void* d_ws, size_t ws_size,
                              hipStream_t stream) {
    const float* enc    = (const float*)d_in[0];
    const int*   align  = (const int*)  d_in[1];
    const int*   text   = (const int*)  d_in[2];
    const float* pitch  = (const float*)d_in[3];
    const int*   beats  = (const int*)  d_in[4];
    const float* wpitch = (const float*)d_in[5];
    const float* bpitch = (const float*)d_in[6];
    const float* embb   = (const float*)d_in[7];
    const float* wpos   = (const float*)d_in[8];
    const float* bpos   = (const float*)d_in[9];
    float* out = (float*)d_out;

    char* ws = (char*)d_ws;
    int*   flags = (int*)  (ws + FLAGS_OFF);
    short* wt    = (short*)(ws + WT_OFF);
    float* pew   = (float*)(ws + PEW_OFF);

    hipLaunchKernelGGL(k_prep, dim3(304), dim3(256), 0, stream,
                       align, text, wpos, bpos, flags, wt, pew);
    hipLaunchKernelGGL(k_fused, dim3(S_ / 4, 4), dim3(256), 0, stream,
                       enc, wt, pew, pitch, beats, wpitch, bpitch, embb,
                       wpos, align, text, flags, bpos, out);
}